// Round 5
// baseline (380.978 us; speedup 1.0000x reference)
//
#include <hip/hip_runtime.h>
#include <math.h>

// Tropical max/min-plus pseudo-matmul.
// out[b,u] = max_f(x[b,f] + w[f,u]) for u<128, min_f otherwise.
//
// R3/R4 lesson: scalar-loading x via SMEM serializes (out-of-order SMEM =>
// every consume drains lgkmcnt(0); SGPR budget forces small batches) ->
// ~30us regardless of occupancy/pipelining. R5: x staged once to LDS,
// inner loop reads it as ds_read_b128 BROADCASTS (all lanes same address,
// conflict-free, in-order fine-grained lgkmcnt). w unchanged: register-
// pipelined dwordx2 stream from L2, lane = 2 units.
// Per-CU: ~12.3k cyc VALU (5.1us floor) vs ~8k cyc LDS issue (underneath).

#define FEAT  512
#define UNITS 256
#define BR    8     // rows per block
#define KW    64    // k per wave
#define NW    8     // waves per block

template<bool IS_MAX>
__device__ __forceinline__ float tmerge(float a, float b) {
    return IS_MAX ? fmaxf(a, b) : fminf(a, b);
}

template<bool IS_MAX>
__device__ __forceinline__ void oct_compute(const float* __restrict__ xs, int kb, int oct,
                                            const float2* __restrict__ wb,
                                            float2* __restrict__ acc) {
    #pragma unroll
    for (int r = 0; r < BR; ++r) {
        // broadcast LDS reads: all 64 lanes same address -> conflict-free
        const float4 a0 = *(const float4*)&xs[r * FEAT + kb + oct * 8];
        const float4 a1 = *(const float4*)&xs[r * FEAT + kb + oct * 8 + 4];
        float2 A = acc[r];
        A.x = tmerge<IS_MAX>(tmerge<IS_MAX>(A.x, a0.x + wb[0].x), a0.y + wb[1].x);
        A.x = tmerge<IS_MAX>(tmerge<IS_MAX>(A.x, a0.z + wb[2].x), a0.w + wb[3].x);
        A.x = tmerge<IS_MAX>(tmerge<IS_MAX>(A.x, a1.x + wb[4].x), a1.y + wb[5].x);
        A.x = tmerge<IS_MAX>(tmerge<IS_MAX>(A.x, a1.z + wb[6].x), a1.w + wb[7].x);
        A.y = tmerge<IS_MAX>(tmerge<IS_MAX>(A.y, a0.x + wb[0].y), a0.y + wb[1].y);
        A.y = tmerge<IS_MAX>(tmerge<IS_MAX>(A.y, a0.z + wb[2].y), a0.w + wb[3].y);
        A.y = tmerge<IS_MAX>(tmerge<IS_MAX>(A.y, a1.x + wb[4].y), a1.y + wb[5].y);
        A.y = tmerge<IS_MAX>(tmerge<IS_MAX>(A.y, a1.z + wb[6].y), a1.w + wb[7].y);
        acc[r] = A;
    }
}

template<bool IS_MAX>
__device__ __forceinline__ void trop_body(const float* __restrict__ x,
                                          const float* __restrict__ w,
                                          float* __restrict__ out,
                                          int ubase, float* __restrict__ lds) {
    const int tid  = threadIdx.x;
    const int lane = tid & 63;
    const int wv   = __builtin_amdgcn_readfirstlane(tid >> 6);  // 0..7
    const int u    = ubase + lane * 2;
    const int row0 = blockIdx.y * BR;
    const int kb   = wv * KW;

    // ---- stage x tile (8 rows x 512 k = 16 KB) into LDS, coalesced float4 ----
    {
        const float4* src = (const float4*)(x + (size_t)row0 * FEAT);
        float4* dst = (float4*)lds;
        dst[tid]       = src[tid];
        dst[tid + 512] = src[tid + 512];
    }

    const float* wp = w + (size_t)kb * UNITS + u;   // lane-strided, 512B/load

    float2 acc[BR];
    const float init = IS_MAX ? -__builtin_inff() : __builtin_inff();
    #pragma unroll
    for (int r = 0; r < BR; ++r) acc[r] = make_float2(init, init);

    // prefetch first w octet while x staging settles
    float2 wA[8], wB[8];
    #pragma unroll
    for (int k = 0; k < 8; ++k) wA[k] = *(const float2*)(wp + (size_t)k * UNITS);

    __syncthreads();   // x tile visible

    #pragma unroll
    for (int oct = 0; oct < KW / 8; oct += 2) {
        #pragma unroll
        for (int k = 0; k < 8; ++k)
            wB[k] = *(const float2*)(wp + (size_t)((oct + 1) * 8 + k) * UNITS);
        oct_compute<IS_MAX>(lds, kb, oct, wA, acc);
        if (oct + 2 < KW / 8) {
            #pragma unroll
            for (int k = 0; k < 8; ++k)
                wA[k] = *(const float2*)(wp + (size_t)((oct + 2) * 8 + k) * UNITS);
        }
        oct_compute<IS_MAX>(lds, kb, oct + 1, wB, acc);
    }

    // ---- combine 8 k-partials via LDS (reuses x region; 32 KB) ----
    __syncthreads();   // all waves done reading x tile
    #pragma unroll
    for (int r = 0; r < BR; ++r)
        *(float2*)&lds[(wv * BR + r) * 128 + lane * 2] = acc[r];
    __syncthreads();

    // wave wv reduces row r == wv; 2-way bank alias on b64 reads (free)
    float2 v = *(const float2*)&lds[(0 * BR + wv) * 128 + lane * 2];
    #pragma unroll
    for (int j = 1; j < NW; ++j) {
        const float2 p = *(const float2*)&lds[(j * BR + wv) * 128 + lane * 2];
        v.x = tmerge<IS_MAX>(v.x, p.x);
        v.y = tmerge<IS_MAX>(v.y, p.y);
    }
    *(float2*)&out[(size_t)(row0 + wv) * UNITS + u] = v;  // 512B coalesced
}

__global__ __launch_bounds__(512, 4) void tropical_kernel(const float* __restrict__ x,
                                                          const float* __restrict__ w,
                                                          float* __restrict__ out) {
    __shared__ float lds[NW * BR * 128];       // 32 KB (x tile uses first 16 KB)
    const int ubase = blockIdx.x * 128;        // 0 -> max half; 128 -> min half
    if (ubase < 128) trop_body<true>(x, w, out, ubase, lds);
    else             trop_body<false>(x, w, out, ubase, lds);
}

extern "C" void kernel_launch(void* const* d_in, const int* in_sizes, int n_in,
                              void* d_out, int out_size, void* d_ws, size_t ws_size,
                              hipStream_t stream) {
    const float* x = (const float*)d_in[0];   // (2048, 512)
    const float* w = (const float*)d_in[1];   // (512, 256)
    float* out = (float*)d_out;               // (2048, 256)

    // 2 u-halves x 256 row-groups = 512 blocks x 8 waves = 4096 waves (4/SIMD)
    dim3 grid(UNITS / 128, 2048 / BR);
    tropical_kernel<<<grid, dim3(512), 0, stream>>>(x, w, out);
}

// Round 6
// 72.660 us; speedup vs baseline: 5.2433x; 5.2433x over previous
//
#include <hip/hip_runtime.h>
#include <math.h>

// Tropical max/min-plus pseudo-matmul.
// out[b,u] = max_f(x[b,f] + w[f,u]) for u<128, min_f otherwise.
//
// R5 lesson: __launch_bounds__(512,4) acted like CUDA blocks-per-CU -> 64-VGPR
// cap -> ~940 MB scratch spill traffic (331us, BW-bound on spills). R3/R4 were
// also silently capped at 64 VGPR -> the ~30us plateau was spill, not SMEM.
// R6: identical structure, launch_bounds(512) only. x staged once to LDS,
// inner loop reads it as ds_read_b128 broadcasts; w register-pipelined (A/B)
// dwordx2 stream from L2, lane = 2 units; in-block k-split (8 waves x 64k),
// LDS combine. Paper model: VALU 12.3k cyc/SIMD vs LDS 24.6k cyc/CU.

#define FEAT  512
#define UNITS 256
#define BR    8     // rows per block
#define KW    64    // k per wave
#define NW    8     // waves per block

template<bool IS_MAX>
__device__ __forceinline__ float tmerge(float a, float b) {
    return IS_MAX ? fmaxf(a, b) : fminf(a, b);
}

template<bool IS_MAX>
__device__ __forceinline__ void oct_compute(const float* __restrict__ xs, int kb, int oct,
                                            const float2* __restrict__ wb,
                                            float2* __restrict__ acc) {
    #pragma unroll
    for (int r = 0; r < BR; ++r) {
        // broadcast LDS reads: all 64 lanes same address -> conflict-free
        const float4 a0 = *(const float4*)&xs[r * FEAT + kb + oct * 8];
        const float4 a1 = *(const float4*)&xs[r * FEAT + kb + oct * 8 + 4];
        float2 A = acc[r];
        A.x = tmerge<IS_MAX>(tmerge<IS_MAX>(A.x, a0.x + wb[0].x), a0.y + wb[1].x);
        A.x = tmerge<IS_MAX>(tmerge<IS_MAX>(A.x, a0.z + wb[2].x), a0.w + wb[3].x);
        A.x = tmerge<IS_MAX>(tmerge<IS_MAX>(A.x, a1.x + wb[4].x), a1.y + wb[5].x);
        A.x = tmerge<IS_MAX>(tmerge<IS_MAX>(A.x, a1.z + wb[6].x), a1.w + wb[7].x);
        A.y = tmerge<IS_MAX>(tmerge<IS_MAX>(A.y, a0.x + wb[0].y), a0.y + wb[1].y);
        A.y = tmerge<IS_MAX>(tmerge<IS_MAX>(A.y, a0.z + wb[2].y), a0.w + wb[3].y);
        A.y = tmerge<IS_MAX>(tmerge<IS_MAX>(A.y, a1.x + wb[4].y), a1.y + wb[5].y);
        A.y = tmerge<IS_MAX>(tmerge<IS_MAX>(A.y, a1.z + wb[6].y), a1.w + wb[7].y);
        acc[r] = A;
    }
}

template<bool IS_MAX>
__device__ __forceinline__ void trop_body(const float* __restrict__ x,
                                          const float* __restrict__ w,
                                          float* __restrict__ out,
                                          int ubase, float* __restrict__ lds) {
    const int tid  = threadIdx.x;
    const int lane = tid & 63;
    const int wv   = __builtin_amdgcn_readfirstlane(tid >> 6);  // 0..7
    const int u    = ubase + lane * 2;
    const int row0 = blockIdx.y * BR;
    const int kb   = wv * KW;

    // ---- stage x tile (8 rows x 512 k = 16 KB) into LDS, coalesced float4 ----
    {
        const float4* src = (const float4*)(x + (size_t)row0 * FEAT);
        float4* dst = (float4*)lds;
        dst[tid]       = src[tid];
        dst[tid + 512] = src[tid + 512];
    }

    const float* wp = w + (size_t)kb * UNITS + u;   // lane-strided, 512B/load

    float2 acc[BR];
    const float init = IS_MAX ? -__builtin_inff() : __builtin_inff();
    #pragma unroll
    for (int r = 0; r < BR; ++r) acc[r] = make_float2(init, init);

    // software pipeline: A/B register buffers for w octets
    float2 wA[8], wB[8];
    #pragma unroll
    for (int k = 0; k < 8; ++k) wA[k] = *(const float2*)(wp + (size_t)k * UNITS);

    __syncthreads();   // x tile visible

    #pragma unroll
    for (int oct = 0; oct < KW / 8; oct += 2) {
        #pragma unroll
        for (int k = 0; k < 8; ++k)
            wB[k] = *(const float2*)(wp + (size_t)((oct + 1) * 8 + k) * UNITS);
        oct_compute<IS_MAX>(lds, kb, oct, wA, acc);
        if (oct + 2 < KW / 8) {
            #pragma unroll
            for (int k = 0; k < 8; ++k)
                wA[k] = *(const float2*)(wp + (size_t)((oct + 2) * 8 + k) * UNITS);
        }
        oct_compute<IS_MAX>(lds, kb, oct + 1, wB, acc);
    }

    // ---- combine 8 k-partials via LDS (reuses x region; 32 KB) ----
    __syncthreads();   // all waves done reading x tile
    #pragma unroll
    for (int r = 0; r < BR; ++r)
        *(float2*)&lds[(wv * BR + r) * 128 + lane * 2] = acc[r];
    __syncthreads();

    // wave wv reduces row r == wv; 2-way bank alias on b64 reads (free)
    float2 v = *(const float2*)&lds[(0 * BR + wv) * 128 + lane * 2];
    #pragma unroll
    for (int j = 1; j < NW; ++j) {
        const float2 p = *(const float2*)&lds[(j * BR + wv) * 128 + lane * 2];
        v.x = tmerge<IS_MAX>(v.x, p.x);
        v.y = tmerge<IS_MAX>(v.y, p.y);
    }
    *(float2*)&out[(size_t)(row0 + wv) * UNITS + u] = v;  // 512B coalesced
}

__global__ __launch_bounds__(512) void tropical_kernel(const float* __restrict__ x,
                                                       const float* __restrict__ w,
                                                       float* __restrict__ out) {
    __shared__ float lds[NW * BR * 128];       // 32 KB (x tile uses first 16 KB)
    const int ubase = blockIdx.x * 128;        // 0 -> max half; 128 -> min half
    if (ubase < 128) trop_body<true>(x, w, out, ubase, lds);
    else             trop_body<false>(x, w, out, ubase, lds);
}

extern "C" void kernel_launch(void* const* d_in, const int* in_sizes, int n_in,
                              void* d_out, int out_size, void* d_ws, size_t ws_size,
                              hipStream_t stream) {
    const float* x = (const float*)d_in[0];   // (2048, 512)
    const float* w = (const float*)d_in[1];   // (512, 256)
    float* out = (float*)d_out;               // (2048, 256)

    // 2 u-halves x 256 row-groups = 512 blocks x 8 waves = 4096 waves
    dim3 grid(UNITS / 128, 2048 / BR);
    tropical_kernel<<<grid, dim3(512), 0, stream>>>(x, w, out);
}